// Round 8
// baseline (1324.090 us; speedup 1.0000x reference)
//
#include <hip/hip_runtime.h>
#include <hip/hip_bf16.h>

#define TPB 256
#define NCODES 1024
#define DIMS 256
#define PIXB 64
#define XPAD 264      // xs row stride (ushorts), R3/R4-proven
#define EPAD 34       // es row stride (ushorts) = 68 B; worst 4-way on af reads, fits 3-block LDS budget
#define XS3 68        // phase-3 fp32 x-stage row stride (floats); 64*68*4 = 17408 B = es size exactly
#define DELTA 3.0f    // screening margin; bf16 dot error worst-case ~2.6 in distance units
#define CAP 6         // candidates per pixel; overflow -> exact full rescan

typedef __attribute__((ext_vector_type(8))) short bf16x8;
typedef __attribute__((ext_vector_type(4))) float f32x4;

__device__ __forceinline__ unsigned fkey(float f) {
    unsigned u = __float_as_uint(f);
    return (u & 0x80000000u) ? ~u : (u | 0x80000000u);
}
__device__ __forceinline__ float funkey(unsigned k) {
    return (k & 0x80000000u) ? __uint_as_float(k & 0x7fffffffu) : __uint_as_float(~k);
}

// ---- prep: ebc = bf16(emb) chunk-major [cc*8+kc][256 codes][4 uint4]; e2 exact fp32 ----
__global__ __launch_bounds__(64) void prep_kernel(const float* __restrict__ emb,
                                                  ushort* __restrict__ ebc,
                                                  float* __restrict__ e2) {
    const int c = blockIdx.x;
    const int l = threadIdx.x;           // lane l holds dims 4l..4l+3
    float4 v = *(const float4*)(emb + (size_t)c * DIMS + 4 * l);
    __hip_bfloat16 h0 = __float2bfloat16(v.x), h1 = __float2bfloat16(v.y);
    __hip_bfloat16 h2 = __float2bfloat16(v.z), h3 = __float2bfloat16(v.w);
    ushort4 u4;
    u4.x = *(ushort*)&h0; u4.y = *(ushort*)&h1; u4.z = *(ushort*)&h2; u4.w = *(ushort*)&h3;
    const int kc   = l >> 3;             // 32-dim chunk
    const int u    = (l & 7) >> 1;       // 16B unit (dims u*8..u*8+7)
    const int half = l & 1;
    *(ushort4*)(ebc + (size_t)((c >> 8) * 8 + kc) * 8192 + ((c & 255) * 4 + u) * 8 + half * 4) = u4;
    float s = v.x * v.x + v.y * v.y + v.z * v.z + v.w * v.w;
#pragma unroll
    for (int off = 1; off < 64; off <<= 1) s += __shfl_xor(s, off);
    if (l == 0) e2[c] = s;
}

__global__ __launch_bounds__(TPB, 2) void vq_kernel(const float* __restrict__ z,
                                                    const float* __restrict__ emb,
                                                    const ushort* __restrict__ ebc,
                                                    const float* __restrict__ e2g,
                                                    int* __restrict__ out) {
    // 33792 + 17408 + 1024 + 256 + 256 + 1536 = 54272 B -> 3 blocks/CU
    __shared__ __align__(16) ushort xs[PIXB * XPAD];   // bf16 x tile [px][dim]
    __shared__ __align__(16) ushort es[256 * EPAD];    // bf16 e tile [code][32d]; phase-3 fp32 stage
    __shared__ float    e2s[256];                      // current cc chunk of e2
    __shared__ unsigned minkey[PIXB];
    __shared__ int      cnt[PIXB];
    __shared__ int      cand[PIXB * CAP];

    const int tid = threadIdx.x;
    const int w   = tid >> 6;
    const int L   = tid & 63;
    const int col = L & 15;       // MFMA col (pixel in B / code in A)
    const int q   = L >> 4;       // MFMA quad (k-slice q*8..q*8+7)
    const int pixbase = blockIdx.x * PIXB;
    const int t  = pixbase >> 12;
    const int n0 = pixbase & 4095;

    // ---- phase 1: coalesced z float4 loads, bf16 transpose into LDS (R4-verified) ----
    {
        const int pq = L & 15;
        const int dq = L >> 4;
#pragma unroll
        for (int i = 0; i < 16; ++i) {
            const int d = w * 64 + i * 4 + dq;
            const float4 v = *(const float4*)(z + (((size_t)(t * DIMS + d)) << 12) + n0 + 4 * pq);
            __hip_bfloat16 h0 = __float2bfloat16(v.x), h1 = __float2bfloat16(v.y);
            __hip_bfloat16 h2 = __float2bfloat16(v.z), h3 = __float2bfloat16(v.w);
            xs[(4 * pq + 0) * XPAD + d] = *(ushort*)&h0;
            xs[(4 * pq + 1) * XPAD + d] = *(ushort*)&h1;
            xs[(4 * pq + 2) * XPAD + d] = *(ushort*)&h2;
            xs[(4 * pq + 3) * XPAD + d] = *(ushort*)&h3;
        }
    }
    if (tid < 64) { minkey[tid] = 0xFFFFFFFFu; cnt[tid] = 0; }

    const uint4* __restrict__ esrc = (const uint4*)ebc;
    const int srow = tid >> 2;          // staging: this thread's code row (j*64 + srow)
    const int sun  = tid & 3;           // staging: 16B unit within row

    // ---- phase 2: MFMA screening with software-pipelined es staging ----
#pragma unroll 1
    for (int cc = 0; cc < 4; ++cc) {
        uint4 rd[4];
        {   // preload kc=0 (coalesced 1 KB/wave/instr); flies during barrier
            const size_t b = (size_t)(cc * 8) * 1024 + tid;
#pragma unroll
            for (int j = 0; j < 4; ++j) rd[j] = esrc[b + j * 256];
        }
        __syncthreads();                  // prev cc fully quiesced (es/e2s/minkey readers done)
        e2s[tid] = e2g[cc * 256 + tid];

        f32x4 acc[4][4];
#pragma unroll
        for (int mt = 0; mt < 4; ++mt)
#pragma unroll
            for (int nt = 0; nt < 4; ++nt) acc[mt][nt] = (f32x4){0.f, 0.f, 0.f, 0.f};

#pragma unroll 1
        for (int kc = 0; kc < 8; ++kc) {
            if (kc) __syncthreads();      // prev af reads done before overwrite
#pragma unroll
            for (int j = 0; j < 4; ++j)   // rd dead after this -> only rdn live through MFMAs
                *(uint4*)&es[(j * 64 + srow) * EPAD + sun * 8] = rd[j];
            if (kc < 7) {                 // issue next chunk's loads; latency hidden under MFMAs
                const size_t b = (size_t)(cc * 8 + kc + 1) * 1024 + tid;
#pragma unroll
                for (int j = 0; j < 4; ++j) rd[j] = esrc[b + j * 256];
            }
            __syncthreads();              // es tile (and e2s on kc=0) visible

            bf16x8 af[4], bfr[4];
#pragma unroll
            for (int mt = 0; mt < 4; ++mt)
                af[mt] = *(const bf16x8*)&es[(w * 64 + mt * 16 + col) * EPAD + q * 8];
#pragma unroll
            for (int nt = 0; nt < 4; ++nt)
                bfr[nt] = *(const bf16x8*)&xs[(nt * 16 + col) * XPAD + kc * 32 + q * 8];
#pragma unroll
            for (int mt = 0; mt < 4; ++mt)
#pragma unroll
                for (int nt = 0; nt < 4; ++nt)
                    acc[mt][nt] = __builtin_amdgcn_mfma_f32_16x16x32_bf16(
                        af[mt], bfr[nt], acc[mt][nt], 0, 0, 0);
        }

        // epilogue: s = e2[c] - 2*dot ; C layout col=px, row=q*4+r_
        f32x4 e2r[4];
#pragma unroll
        for (int mt = 0; mt < 4; ++mt)
            e2r[mt] = *(const f32x4*)&e2s[w * 64 + mt * 16 + q * 4];
#pragma unroll
        for (int nt = 0; nt < 4; ++nt) {
            float m = 3.4e38f;
#pragma unroll
            for (int mt = 0; mt < 4; ++mt)
#pragma unroll
                for (int r_ = 0; r_ < 4; ++r_)
                    m = fminf(m, e2r[mt][r_] - 2.f * acc[mt][nt][r_]);
            m = fminf(m, __shfl_xor(m, 16));
            m = fminf(m, __shfl_xor(m, 32));
            if (q == 0) atomicMin(&minkey[nt * 16 + col], fkey(m));
        }
        __syncthreads();                  // minkey updates visible
#pragma unroll
        for (int nt = 0; nt < 4; ++nt) {
            const int px = nt * 16 + col;
            const float thr = funkey(minkey[px]) + DELTA;   // running min -> superset guarantee
#pragma unroll
            for (int mt = 0; mt < 4; ++mt)
#pragma unroll
                for (int r_ = 0; r_ < 4; ++r_) {
                    float s = e2r[mt][r_] - 2.f * acc[mt][nt][r_];
                    if (s <= thr) {
                        int pos = atomicAdd(&cnt[px], 1);
                        if (pos < CAP)
                            cand[px * CAP + pos] = cc * 256 + w * 64 + mt * 16 + q * 4 + r_;
                    }
                }
        }
    }
    __syncthreads();                      // candidate lists final; es dead -> reuse as x-stage

    // ---- phase 3: exact fp32 rescore from LDS-staged z chunks (R6-verified) ----
    float* xstage = (float*)es;           // 64 x XS3 fp32 = 17408 B
    const int px  = w * 16 + (L & 15);
    const int n   = cnt[px];
    const bool ovf = (n > CAP);
    const int ns  = ovf ? 0 : n;
    const int s0  = L >> 4;               // lane's candidate slots: s0, s0+4
    const int c0  = (s0 < ns)     ? cand[px * CAP + s0]     : -1;
    const int c1  = (s0 + 4 < ns) ? cand[px * CAP + s0 + 4] : -1;
    float a0 = 0.f, a1 = 0.f;

#pragma unroll 1
    for (int dc = 0; dc < 4; ++dc) {
        if (dc) __syncthreads();
        {   // stage 64 dims x 64 px fp32; lane L = px (coalesced 256B per instr)
            const float* zp = z + (((size_t)(t * DIMS + dc * 64 + w * 16)) << 12) + n0 + L;
            float* xrow = xstage + L * XS3 + w * 16;
#pragma unroll
            for (int j = 0; j < 16; ++j)
                xrow[j] = zp[(size_t)j << 12];
        }
        __syncthreads();
        const float* xv = xstage + px * XS3;
        if (c0 >= 0) {
            const float4* ep = (const float4*)(emb + (size_t)c0 * DIMS + dc * 64);
#pragma unroll
            for (int d4 = 0; d4 < 16; ++d4) {
                float4 x4 = *(const float4*)(xv + 4 * d4);
                float4 e4 = ep[d4];
                a0 += x4.x * e4.x + x4.y * e4.y + x4.z * e4.z + x4.w * e4.w;
            }
        }
        if (c1 >= 0) {
            const float4* ep = (const float4*)(emb + (size_t)c1 * DIMS + dc * 64);
#pragma unroll
            for (int d4 = 0; d4 < 16; ++d4) {
                float4 x4 = *(const float4*)(xv + 4 * d4);
                float4 e4 = ep[d4];
                a1 += x4.x * e4.x + x4.y * e4.y + x4.z * e4.z + x4.w * e4.w;
            }
        }
    }
    {   // per-lane best of 2 slots, then combine the 4 lanes sharing this px
        float bd = 3.4e38f; int bi_ = 0x7fffffff;
        if (c0 >= 0) { float s = e2g[c0] - 2.f * a0; if (s < bd || (s == bd && c0 < bi_)) { bd = s; bi_ = c0; } }
        if (c1 >= 0) { float s = e2g[c1] - 2.f * a1; if (s < bd || (s == bd && c1 < bi_)) { bd = s; bi_ = c1; } }
#pragma unroll
        for (int off = 16; off < 64; off <<= 1) {
            float d2 = __shfl_xor(bd, off);
            int   i2 = __shfl_xor(bi_, off);
            if (d2 < bd || (d2 == bd && i2 < bi_)) { bd = d2; bi_ = i2; }
        }
        if (L < 16 && !ovf) out[pixbase + px] = bi_;
    }

    // overflow fallback (rare): exact full scan
#pragma unroll 1
    for (int pi = 0; pi < 16; ++pi) {
        const int fpx = w * 16 + pi;
        if (cnt[fpx] <= CAP) continue;    // wave-uniform
        const float* zp = z + (((size_t)t * DIMS + 4 * L) << 12) + n0 + fpx;
        float x0 = zp[0];
        float x1 = zp[(size_t)1 << 12];
        float x2 = zp[(size_t)2 << 12];
        float x3 = zp[(size_t)3 << 12];
        float bs = 3.4e38f;
        int   bi = 0;
        for (int c = 0; c < NCODES; ++c) {
            float4 ev = *(const float4*)(emb + (size_t)c * DIMS + 4 * L);
            float p = x0 * ev.x + x1 * ev.y + x2 * ev.z + x3 * ev.w;
#pragma unroll
            for (int off = 1; off < 64; off <<= 1) p += __shfl_xor(p, off);
            float s = e2g[c] - 2.f * p;
            if (s < bs || (s == bs && c < bi)) { bs = s; bi = c; }
        }
        if (L == 0) out[pixbase + fpx] = bi;
    }
}

extern "C" void kernel_launch(void* const* d_in, const int* in_sizes, int n_in,
                              void* d_out, int out_size, void* d_ws, size_t ws_size,
                              hipStream_t stream) {
    const float* z   = (const float*)d_in[0];   // (16,256,64,64) fp32
    const float* emb = (const float*)d_in[1];   // (1024,256) fp32
    int* out = (int*)d_out;                     // (16,64,64) int32

    ushort* ebc = (ushort*)d_ws;                                         // 512 KB chunk-major bf16
    float*  e2  = (float*)((char*)d_ws + (size_t)NCODES * DIMS * sizeof(ushort)); // 4 KB

    prep_kernel<<<NCODES, 64, 0, stream>>>(emb, ebc, e2);
    vq_kernel<<<(16 * 64 * 64) / PIXB, TPB, 0, stream>>>(z, emb, ebc, e2, out);
}